// Round 1
// baseline (3378.284 us; speedup 1.0000x reference)
//
#include <hip/hip_runtime.h>
#include <math.h>

#define N_NODES 50000
#define N_EDGES 800000
#define IN_C 128
#define HID_C 96
#define OUT_C 64
#define BN_EPS 1e-5f

// ---------------------------------------------------------------------------
// GEMM: h[n,j] = sum_k x[n,k] * W[k,j].  W staged in LDS (max 48 KB for 128x96).
// One thread per (node, out-channel). x[n,k] is a wave-broadcast load (all
// lanes of a wave share n except at J boundaries); W from LDS.
// ---------------------------------------------------------------------------
template <int K, int J>
__global__ void gemm_kernel(const float* __restrict__ x,
                            const float* __restrict__ W,
                            float* __restrict__ h, int N) {
    __shared__ float Ws[K * J];
    for (int i = threadIdx.x; i < K * J; i += blockDim.x) Ws[i] = W[i];
    __syncthreads();
    int t = blockIdx.x * blockDim.x + threadIdx.x;
    if (t >= N * J) return;
    int n = t / J, j = t % J;
    const float* xr = x + (long)n * K;
    float acc = 0.f;
#pragma unroll 8
    for (int k = 0; k < K; ++k) acc += xr[k] * Ws[k * J + j];
    h[t] = acc;
}

// ---------------------------------------------------------------------------
// Edge scatter: agg[row[e],:] += ew[e] * h[col[e],:]
// Thread per (edge, 4-channel group): float4 gather (coalesced across the
// D/4 consecutive threads of an edge), 4 scalar fp32 global atomics.
// ---------------------------------------------------------------------------
template <int D>
__global__ void scatter_kernel(const float* __restrict__ h,
                               const float* __restrict__ ew,
                               const int* __restrict__ row,
                               const int* __restrict__ col,
                               float* __restrict__ agg) {
    const int G = D / 4;
    int t = blockIdx.x * blockDim.x + threadIdx.x;
    if (t >= N_EDGES * G) return;
    int e = t / G, g = t % G;
    float w = ew[e];
    int c = col[e], r = row[e];
    float4 v = *(const float4*)(h + (long)c * D + g * 4);
    float* dst = agg + (long)r * D + g * 4;
    atomicAdd(dst + 0, w * v.x);
    atomicAdd(dst + 1, w * v.y);
    atomicAdd(dst + 2, w * v.z);
    atomicAdd(dst + 3, w * v.w);
}

// ---------------------------------------------------------------------------
// BN stats: per-channel sum and sum-of-squares over N nodes.
// Grid-stride over the flat [N*D] array (coalesced); LDS-atomic partials per
// block (64 consecutive lanes hit 64 distinct channels -> near-conflict-free),
// one global atomic per channel per block at the end.
// ---------------------------------------------------------------------------
template <int D>
__global__ void bn_stats_kernel(const float* __restrict__ a,
                                float* __restrict__ sums, int N) {
    __shared__ float s[D], ss[D];
    for (int i = threadIdx.x; i < D; i += blockDim.x) { s[i] = 0.f; ss[i] = 0.f; }
    __syncthreads();
    int total = N * D;
    for (int idx = blockIdx.x * blockDim.x + threadIdx.x; idx < total;
         idx += gridDim.x * blockDim.x) {
        float v = a[idx];
        int ch = idx % D;
        atomicAdd(&s[ch], v);
        atomicAdd(&ss[ch], v * v);
    }
    __syncthreads();
    for (int i = threadIdx.x; i < D; i += blockDim.x) {
        atomicAdd(&sums[i], s[i]);
        atomicAdd(&sums[D + i], ss[i]);
    }
}

// Fold mean/var + gamma/beta into per-channel scale/shift.
// NOTE: conv bias b cancels in BN: (agg + b - (mean_agg + b)) == agg - mean_agg,
// so b1/b2 never enter the computation.
template <int D>
__global__ void bn_finalize_kernel(const float* __restrict__ sums,
                                   const float* __restrict__ g,
                                   const float* __restrict__ be,
                                   float* __restrict__ scsh, float invN) {
    int c = threadIdx.x;
    if (c < D) {
        float mean = sums[c] * invN;
        float var = sums[D + c] * invN - mean * mean;
        float sc = g[c] * rsqrtf(var + BN_EPS);
        scsh[c] = sc;
        scsh[D + c] = be[c] - mean * sc;
    }
}

// y = relu(a*scale + shift), in-place safe.
template <int D>
__global__ void bn_apply_kernel(const float* __restrict__ a,
                                const float* __restrict__ scsh,
                                float* __restrict__ y, int N) {
    int idx = blockIdx.x * blockDim.x + threadIdx.x;
    if (idx >= N * D) return;
    int c = idx % D;
    float v = a[idx] * scsh[c] + scsh[D + c];
    y[idx] = v > 0.f ? v : 0.f;
}

// ---------------------------------------------------------------------------
// Final: out[n,:] = log_softmax(agg[n,:] + b3).  OUT_C == 64 == wave size:
// one wave per node, pure shuffle reductions.
// ---------------------------------------------------------------------------
__global__ void lsm_kernel(const float* __restrict__ agg,
                           const float* __restrict__ b,
                           float* __restrict__ out, int N) {
    int wave = (blockIdx.x * blockDim.x + threadIdx.x) >> 6;
    int lane = threadIdx.x & 63;
    if (wave >= N) return;
    float v = agg[(long)wave * OUT_C + lane] + b[lane];
    float m = v;
#pragma unroll
    for (int off = 32; off > 0; off >>= 1) m = fmaxf(m, __shfl_xor(m, off, 64));
    float e = expf(v - m);
    float s = e;
#pragma unroll
    for (int off = 32; off > 0; off >>= 1) s += __shfl_xor(s, off, 64);
    out[(long)wave * OUT_C + lane] = v - m - logf(s);
}

extern "C" void kernel_launch(void* const* d_in, const int* in_sizes, int n_in,
                              void* d_out, int out_size, void* d_ws, size_t ws_size,
                              hipStream_t stream) {
    const float* x   = (const float*)d_in[0];
    const float* ew  = (const float*)d_in[1];
    const int*   row = (const int*)d_in[2];
    const int*   col = (const int*)d_in[3];
    const float* W1  = (const float*)d_in[4];
    // b1 = d_in[5], b2 = d_in[7]: cancel inside BatchNorm (see bn_finalize).
    const float* W2  = (const float*)d_in[6];
    const float* W3  = (const float*)d_in[8];
    const float* b3  = (const float*)d_in[9];
    const float* g1  = (const float*)d_in[10];
    const float* be1 = (const float*)d_in[11];
    const float* g2  = (const float*)d_in[12];
    const float* be2 = (const float*)d_in[13];
    float* out = (float*)d_out;

    // Workspace layout (fp32): A[N*96] | B[N*96] | stats[2*96] | scsh[2*96]
    float* A     = (float*)d_ws;
    float* B     = A + (size_t)N_NODES * HID_C;
    float* stats = B + (size_t)N_NODES * HID_C;
    float* scsh  = stats + 2 * HID_C;

    const int T = 256;
    const int gridNH = (N_NODES * HID_C + T - 1) / T;   // N*96 elementwise
    const int gridS96 = (N_EDGES * (HID_C / 4) + T - 1) / T;
    const int gridS64 = (N_EDGES * (OUT_C / 4) + T - 1) / T;

    // ---- Layer 1: GCNConv(128->96) + BN + ReLU ----
    gemm_kernel<IN_C, HID_C><<<gridNH, T, 0, stream>>>(x, W1, A, N_NODES);
    hipMemsetAsync(B, 0, (size_t)N_NODES * HID_C * sizeof(float), stream);
    scatter_kernel<HID_C><<<gridS96, T, 0, stream>>>(A, ew, row, col, B);
    hipMemsetAsync(stats, 0, 2 * HID_C * sizeof(float), stream);
    bn_stats_kernel<HID_C><<<1024, T, 0, stream>>>(B, stats, N_NODES);
    bn_finalize_kernel<HID_C><<<1, 128, 0, stream>>>(stats, g1, be1, scsh, 1.f / N_NODES);
    bn_apply_kernel<HID_C><<<gridNH, T, 0, stream>>>(B, scsh, B, N_NODES);

    // ---- Layer 2: GCNConv(96->96) + BN + ReLU ----
    gemm_kernel<HID_C, HID_C><<<gridNH, T, 0, stream>>>(B, W2, A, N_NODES);
    hipMemsetAsync(B, 0, (size_t)N_NODES * HID_C * sizeof(float), stream);
    scatter_kernel<HID_C><<<gridS96, T, 0, stream>>>(A, ew, row, col, B);
    hipMemsetAsync(stats, 0, 2 * HID_C * sizeof(float), stream);
    bn_stats_kernel<HID_C><<<1024, T, 0, stream>>>(B, stats, N_NODES);
    bn_finalize_kernel<HID_C><<<1, 128, 0, stream>>>(stats, g2, be2, scsh, 1.f / N_NODES);
    bn_apply_kernel<HID_C><<<gridNH, T, 0, stream>>>(B, scsh, B, N_NODES);

    // ---- Layer 3: GCNConv(96->64) + log_softmax ----
    const int gridN64 = (N_NODES * OUT_C + T - 1) / T;
    gemm_kernel<HID_C, OUT_C><<<gridN64, T, 0, stream>>>(B, W3, A, N_NODES);
    hipMemsetAsync(B, 0, (size_t)N_NODES * OUT_C * sizeof(float), stream);
    scatter_kernel<OUT_C><<<gridS64, T, 0, stream>>>(A, ew, row, col, B);
    lsm_kernel<<<(N_NODES + 3) / 4, T, 0, stream>>>(B, b3, out, N_NODES);
}

// Round 2
// 980.579 us; speedup vs baseline: 3.4452x; 3.4452x over previous
//
#include <hip/hip_runtime.h>
#include <math.h>

#define N_NODES 50000
#define N_EDGES 800000
#define IN_C 128
#define HID_C 96
#define OUT_C 64
#define BN_EPS 1e-5f

// ---------------------------------------------------------------------------
// GEMM: h[n,j] = sum_k x[n,k] * W[k,j].  W staged in LDS.
// One thread per (node, out-channel). x[n,k] is a wave-broadcast load.
// ---------------------------------------------------------------------------
template <int K, int J>
__global__ void gemm_kernel(const float* __restrict__ x,
                            const float* __restrict__ W,
                            float* __restrict__ h, int N) {
    __shared__ float Ws[K * J];
    for (int i = threadIdx.x; i < K * J; i += blockDim.x) Ws[i] = W[i];
    __syncthreads();
    int t = blockIdx.x * blockDim.x + threadIdx.x;
    if (t >= N * J) return;
    int n = t / J, j = t % J;
    const float* xr = x + (long)n * K;
    float acc = 0.f;
#pragma unroll 8
    for (int k = 0; k < K; ++k) acc += xr[k] * Ws[k * J + j];
    h[t] = acc;
}

// ---------------------------------------------------------------------------
// CSR build: histogram -> single-block scan -> permute-fill.
// Edge order within a row is nondeterministic (atomic slot grab) — only
// perturbs fp32 summation order, well inside threshold.
// ---------------------------------------------------------------------------
__global__ void hist_kernel(const int* __restrict__ row, int* __restrict__ deg) {
    int e = blockIdx.x * blockDim.x + threadIdx.x;
    if (e < N_EDGES) atomicAdd(&deg[row[e]], 1);
}

// One block, 1024 threads: chunked sequential sums + LDS log-step scan.
__global__ void scan_kernel(const int* __restrict__ deg, int* __restrict__ rowptr) {
    __shared__ int bs[1024];
    int tid = threadIdx.x;
    const int chunk = (N_NODES + 1023) / 1024;
    int beg = tid * chunk;
    int end = min(beg + chunk, N_NODES);
    int s = 0;
    for (int i = beg; i < end; ++i) s += deg[i];
    bs[tid] = s;
    __syncthreads();
    for (int off = 1; off < 1024; off <<= 1) {
        int v = 0;
        if (tid >= off) v = bs[tid - off];
        __syncthreads();
        if (tid >= off) bs[tid] += v;
        __syncthreads();
    }
    int run = (tid > 0) ? bs[tid - 1] : 0;
    for (int i = beg; i < end; ++i) { rowptr[i] = run; run += deg[i]; }
    if (tid == 0) rowptr[N_NODES] = bs[1023];
}

// pairs[idx] = (col, edge_weight) sorted by destination row.
__global__ void fill_kernel(const int* __restrict__ row, const int* __restrict__ col,
                            const float* __restrict__ ew, int* __restrict__ pos,
                            int2* __restrict__ pairs) {
    int e = blockIdx.x * blockDim.x + threadIdx.x;
    if (e >= N_EDGES) return;
    int idx = atomicAdd(&pos[row[e]], 1);
    pairs[idx] = make_int2(col[e], __float_as_int(ew[e]));
}

// ---------------------------------------------------------------------------
// CSR aggregation (replaces atomic scatter): one thread per (node, float4
// group). G consecutive lanes share a node -> pairs/rowptr loads broadcast,
// the h-row gather is a coalesced 384B (D=96) / 256B (D=64) segment.
// Register accumulate, single coalesced write. Zero-degree rows write 0.
// ---------------------------------------------------------------------------
template <int D>
__global__ void agg_csr_kernel(const float* __restrict__ h,
                               const int* __restrict__ rowptr,
                               const int2* __restrict__ pairs,
                               float* __restrict__ out) {
    const int G = D / 4;
    int t = blockIdx.x * blockDim.x + threadIdx.x;
    if (t >= N_NODES * G) return;
    int n = t / G, g = t % G;
    int beg = rowptr[n], end = rowptr[n + 1];
    float4 acc = make_float4(0.f, 0.f, 0.f, 0.f);
    for (int i = beg; i < end; ++i) {
        int2 p = pairs[i];
        float w = __int_as_float(p.y);
        const float4 v = *(const float4*)(h + (size_t)p.x * D + g * 4);
        acc.x += w * v.x; acc.y += w * v.y; acc.z += w * v.z; acc.w += w * v.w;
    }
    *(float4*)(out + (size_t)n * D + g * 4) = acc;
}

// ---------------------------------------------------------------------------
// BN stats: per-channel sum / sum-of-squares, LDS-atomic partials per block.
// ---------------------------------------------------------------------------
template <int D>
__global__ void bn_stats_kernel(const float* __restrict__ a,
                                float* __restrict__ sums, int N) {
    __shared__ float s[D], ss[D];
    for (int i = threadIdx.x; i < D; i += blockDim.x) { s[i] = 0.f; ss[i] = 0.f; }
    __syncthreads();
    int total = N * D;
    for (int idx = blockIdx.x * blockDim.x + threadIdx.x; idx < total;
         idx += gridDim.x * blockDim.x) {
        float v = a[idx];
        int ch = idx % D;
        atomicAdd(&s[ch], v);
        atomicAdd(&ss[ch], v * v);
    }
    __syncthreads();
    for (int i = threadIdx.x; i < D; i += blockDim.x) {
        atomicAdd(&sums[i], s[i]);
        atomicAdd(&sums[D + i], ss[i]);
    }
}

// Fold mean/var + gamma/beta into scale/shift. Conv bias b cancels in BN.
template <int D>
__global__ void bn_finalize_kernel(const float* __restrict__ sums,
                                   const float* __restrict__ g,
                                   const float* __restrict__ be,
                                   float* __restrict__ scsh, float invN) {
    int c = threadIdx.x;
    if (c < D) {
        float mean = sums[c] * invN;
        float var = sums[D + c] * invN - mean * mean;
        float sc = g[c] * rsqrtf(var + BN_EPS);
        scsh[c] = sc;
        scsh[D + c] = be[c] - mean * sc;
    }
}

// y = relu(a*scale + shift), in-place safe.
template <int D>
__global__ void bn_apply_kernel(const float* __restrict__ a,
                                const float* __restrict__ scsh,
                                float* __restrict__ y, int N) {
    int idx = blockIdx.x * blockDim.x + threadIdx.x;
    if (idx >= N * D) return;
    int c = idx % D;
    float v = a[idx] * scsh[c] + scsh[D + c];
    y[idx] = v > 0.f ? v : 0.f;
}

// ---------------------------------------------------------------------------
// out[n,:] = log_softmax(agg[n,:] + b3). OUT_C == 64 == wave: shuffle reduce.
// In-place safe (each thread reads its own element before the write).
// ---------------------------------------------------------------------------
__global__ void lsm_kernel(const float* __restrict__ agg,
                           const float* __restrict__ b,
                           float* __restrict__ out, int N) {
    int wave = (blockIdx.x * blockDim.x + threadIdx.x) >> 6;
    int lane = threadIdx.x & 63;
    if (wave >= N) return;
    float v = agg[(long)wave * OUT_C + lane] + b[lane];
    float m = v;
#pragma unroll
    for (int off = 32; off > 0; off >>= 1) m = fmaxf(m, __shfl_xor(m, off, 64));
    float e = expf(v - m);
    float s = e;
#pragma unroll
    for (int off = 32; off > 0; off >>= 1) s += __shfl_xor(s, off, 64);
    out[(long)wave * OUT_C + lane] = v - m - logf(s);
}

extern "C" void kernel_launch(void* const* d_in, const int* in_sizes, int n_in,
                              void* d_out, int out_size, void* d_ws, size_t ws_size,
                              hipStream_t stream) {
    const float* x   = (const float*)d_in[0];
    const float* ew  = (const float*)d_in[1];
    const int*   row = (const int*)d_in[2];
    const int*   col = (const int*)d_in[3];
    const float* W1  = (const float*)d_in[4];
    // b1 = d_in[5], b2 = d_in[7]: cancel inside BatchNorm (see bn_finalize).
    const float* W2  = (const float*)d_in[6];
    const float* W3  = (const float*)d_in[8];
    const float* b3  = (const float*)d_in[9];
    const float* g1  = (const float*)d_in[10];
    const float* be1 = (const float*)d_in[11];
    const float* g2  = (const float*)d_in[12];
    const float* be2 = (const float*)d_in[13];
    float* out = (float*)d_out;

    // Workspace (all offsets 16B-aligned):
    // A[N*96] | B[N*96] | stats[192] | scsh[192] | pairs[E int2] | rowptr[N+1] | pos[N]
    float* A     = (float*)d_ws;
    float* B     = A + (size_t)N_NODES * HID_C;
    float* stats = B + (size_t)N_NODES * HID_C;
    float* scsh  = stats + 2 * HID_C;
    int2*  pairs = (int2*)(scsh + 2 * HID_C);
    int*   rowptr = (int*)(pairs + N_EDGES);
    int*   pos    = rowptr + (N_NODES + 1);

    const int T = 256;
    const int gridE   = (N_EDGES + T - 1) / T;
    const int gridNH  = (N_NODES * HID_C + T - 1) / T;
    const int gridN64 = (N_NODES * OUT_C + T - 1) / T;
    const int gridA96 = (N_NODES * (HID_C / 4) + T - 1) / T;
    const int gridA64 = (N_NODES * (OUT_C / 4) + T - 1) / T;

    // ---- CSR build (reused by all 3 layers) ----
    hipMemsetAsync(pos, 0, N_NODES * sizeof(int), stream);          // pos doubles as deg
    hist_kernel<<<gridE, T, 0, stream>>>(row, pos);
    scan_kernel<<<1, 1024, 0, stream>>>(pos, rowptr);
    hipMemcpyAsync(pos, rowptr, N_NODES * sizeof(int), hipMemcpyDeviceToDevice, stream);
    fill_kernel<<<gridE, T, 0, stream>>>(row, col, ew, pos, pairs);

    // ---- Layer 1: GCNConv(128->96) + BN + ReLU ----
    gemm_kernel<IN_C, HID_C><<<gridNH, T, 0, stream>>>(x, W1, A, N_NODES);
    agg_csr_kernel<HID_C><<<gridA96, T, 0, stream>>>(A, rowptr, pairs, B);
    hipMemsetAsync(stats, 0, 2 * HID_C * sizeof(float), stream);
    bn_stats_kernel<HID_C><<<1024, T, 0, stream>>>(B, stats, N_NODES);
    bn_finalize_kernel<HID_C><<<1, 128, 0, stream>>>(stats, g1, be1, scsh, 1.f / N_NODES);
    bn_apply_kernel<HID_C><<<gridNH, T, 0, stream>>>(B, scsh, B, N_NODES);

    // ---- Layer 2: GCNConv(96->96) + BN + ReLU ----
    gemm_kernel<HID_C, HID_C><<<gridNH, T, 0, stream>>>(B, W2, A, N_NODES);
    agg_csr_kernel<HID_C><<<gridA96, T, 0, stream>>>(A, rowptr, pairs, B);
    hipMemsetAsync(stats, 0, 2 * HID_C * sizeof(float), stream);
    bn_stats_kernel<HID_C><<<1024, T, 0, stream>>>(B, stats, N_NODES);
    bn_finalize_kernel<HID_C><<<1, 128, 0, stream>>>(stats, g2, be2, scsh, 1.f / N_NODES);
    bn_apply_kernel<HID_C><<<gridNH, T, 0, stream>>>(B, scsh, B, N_NODES);

    // ---- Layer 3: GCNConv(96->64) + log_softmax (agg direct into d_out) ----
    gemm_kernel<HID_C, OUT_C><<<gridN64, T, 0, stream>>>(B, W3, A, N_NODES);
    agg_csr_kernel<OUT_C><<<gridA64, T, 0, stream>>>(A, rowptr, pairs, out);
    lsm_kernel<<<(N_NODES + 3) / 4, T, 0, stream>>>(out, b3, out, N_NODES);
}

// Round 3
// 610.222 us; speedup vs baseline: 5.5362x; 1.6069x over previous
//
#include <hip/hip_runtime.h>
#include <math.h>

#define N_NODES 50000
#define N_EDGES 800000
#define IN_C 128
#define HID_C 96
#define OUT_C 64
#define BN_EPS 1e-5f

// ---------------------------------------------------------------------------
// Register-tiled GEMM: h[N,J] = x[N,K] @ W[K,J].
// Tile: 64 nodes x J channels per block. W fully in LDS; x staged transposed
// (XsT[k][node], +4 pad) in K-chunks of 32. Thread = (tx channel-group of 4,
// ty node-group of 4): per k, one float4 a (4 nodes), one float4 b (4 chans),
// 16 FMAs. Block = (J/4)*16 threads (384 for J=96, 256 for J=64).
// ---------------------------------------------------------------------------
template <int K, int J>
__global__ void gemm_tiled(const float* __restrict__ x,
                           const float* __restrict__ W,
                           float* __restrict__ h, int N) {
    constexpr int MT = 64, TM = 4, TN = 4, KB = 32;
    constexpr int TX = J / TN;       // 24 (J=96) or 16 (J=64)
    constexpr int XP = MT + 4;       // padded XsT row: breaks 4-way bank alias
    __shared__ __align__(16) float Ws[K * J];
    __shared__ __align__(16) float XsT[KB * XP];

    int tid = threadIdx.x;
    int tx = tid % TX, ty = tid / TX;
    int tileBase = blockIdx.x * MT;

    for (int i = tid; i < K * J / 4; i += blockDim.x)
        ((float4*)Ws)[i] = ((const float4*)W)[i];

    float4 acc[TM];
#pragma unroll
    for (int tm = 0; tm < TM; ++tm) acc[tm] = make_float4(0.f, 0.f, 0.f, 0.f);

    for (int k0 = 0; k0 < K; k0 += KB) {
        __syncthreads();   // Ws ready (iter 0) / previous chunk consumed
        // Stage 64 nodes x KB ks, transposed. float4 global read -> 4 LDS writes.
        for (int i = tid; i < MT * (KB / 4); i += blockDim.x) {
            int node = i / (KB / 4), kq = i % (KB / 4);
            int gn = min(tileBase + node, N - 1);   // clamp: edge tile
            float4 v = *(const float4*)(x + (size_t)gn * K + k0 + kq * 4);
            XsT[(kq * 4 + 0) * XP + node] = v.x;
            XsT[(kq * 4 + 1) * XP + node] = v.y;
            XsT[(kq * 4 + 2) * XP + node] = v.z;
            XsT[(kq * 4 + 3) * XP + node] = v.w;
        }
        __syncthreads();
#pragma unroll 8
        for (int kk = 0; kk < KB; ++kk) {
            float4 a = *(const float4*)&XsT[kk * XP + ty * TM];
            float4 b = *(const float4*)&Ws[(k0 + kk) * J + tx * TN];
#pragma unroll
            for (int tm = 0; tm < TM; ++tm) {
                float av = ((const float*)&a)[tm];
                acc[tm].x += av * b.x;
                acc[tm].y += av * b.y;
                acc[tm].z += av * b.z;
                acc[tm].w += av * b.w;
            }
        }
    }
#pragma unroll
    for (int tm = 0; tm < TM; ++tm) {
        int n = tileBase + ty * TM + tm;
        if (n < N) *(float4*)(h + (size_t)n * J + tx * TN) = acc[tm];
    }
}

// ---------------------------------------------------------------------------
// CSR build: histogram -> single-block scan -> permute-fill.
// ---------------------------------------------------------------------------
__global__ void hist_kernel(const int* __restrict__ row, int* __restrict__ deg) {
    int e = blockIdx.x * blockDim.x + threadIdx.x;
    if (e < N_EDGES) atomicAdd(&deg[row[e]], 1);
}

__global__ void scan_kernel(const int* __restrict__ deg, int* __restrict__ rowptr) {
    __shared__ int bs[1024];
    int tid = threadIdx.x;
    const int chunk = (N_NODES + 1023) / 1024;
    int beg = tid * chunk;
    int end = min(beg + chunk, N_NODES);
    int s = 0;
    for (int i = beg; i < end; ++i) s += deg[i];
    bs[tid] = s;
    __syncthreads();
    for (int off = 1; off < 1024; off <<= 1) {
        int v = 0;
        if (tid >= off) v = bs[tid - off];
        __syncthreads();
        if (tid >= off) bs[tid] += v;
        __syncthreads();
    }
    int run = (tid > 0) ? bs[tid - 1] : 0;
    for (int i = beg; i < end; ++i) { rowptr[i] = run; run += deg[i]; }
    if (tid == 0) rowptr[N_NODES] = bs[1023];
}

__global__ void fill_kernel(const int* __restrict__ row, const int* __restrict__ col,
                            const float* __restrict__ ew, int* __restrict__ pos,
                            int2* __restrict__ pairs) {
    int e = blockIdx.x * blockDim.x + threadIdx.x;
    if (e >= N_EDGES) return;
    int idx = atomicAdd(&pos[row[e]], 1);
    pairs[idx] = make_int2(col[e], __float_as_int(ew[e]));
}

// ---------------------------------------------------------------------------
// CSR aggregation: thread per (node, float4 group); register accumulate.
// ---------------------------------------------------------------------------
template <int D>
__global__ void agg_csr_kernel(const float* __restrict__ h,
                               const int* __restrict__ rowptr,
                               const int2* __restrict__ pairs,
                               float* __restrict__ out) {
    const int G = D / 4;
    int t = blockIdx.x * blockDim.x + threadIdx.x;
    if (t >= N_NODES * G) return;
    int n = t / G, g = t % G;
    int beg = rowptr[n], end = rowptr[n + 1];
    float4 acc = make_float4(0.f, 0.f, 0.f, 0.f);
    for (int i = beg; i < end; ++i) {
        int2 p = pairs[i];
        float w = __int_as_float(p.y);
        const float4 v = *(const float4*)(h + (size_t)p.x * D + g * 4);
        acc.x += w * v.x; acc.y += w * v.y; acc.z += w * v.z; acc.w += w * v.w;
    }
    *(float4*)(out + (size_t)n * D + g * 4) = acc;
}

// ---------------------------------------------------------------------------
// BN stats + finalize + apply. Conv bias cancels inside BN.
// ---------------------------------------------------------------------------
template <int D>
__global__ void bn_stats_kernel(const float* __restrict__ a,
                                float* __restrict__ sums, int N) {
    __shared__ float s[D], ss[D];
    for (int i = threadIdx.x; i < D; i += blockDim.x) { s[i] = 0.f; ss[i] = 0.f; }
    __syncthreads();
    int total = N * D;
    for (int idx = blockIdx.x * blockDim.x + threadIdx.x; idx < total;
         idx += gridDim.x * blockDim.x) {
        float v = a[idx];
        int ch = idx % D;
        atomicAdd(&s[ch], v);
        atomicAdd(&ss[ch], v * v);
    }
    __syncthreads();
    for (int i = threadIdx.x; i < D; i += blockDim.x) {
        atomicAdd(&sums[i], s[i]);
        atomicAdd(&sums[D + i], ss[i]);
    }
}

template <int D>
__global__ void bn_finalize_kernel(const float* __restrict__ sums,
                                   const float* __restrict__ g,
                                   const float* __restrict__ be,
                                   float* __restrict__ scsh, float invN) {
    int c = threadIdx.x;
    if (c < D) {
        float mean = sums[c] * invN;
        float var = sums[D + c] * invN - mean * mean;
        float sc = g[c] * rsqrtf(var + BN_EPS);
        scsh[c] = sc;
        scsh[D + c] = be[c] - mean * sc;
    }
}

template <int D>
__global__ void bn_apply_kernel(const float* __restrict__ a,
                                const float* __restrict__ scsh,
                                float* __restrict__ y, int N) {
    int idx = blockIdx.x * blockDim.x + threadIdx.x;
    if (idx >= N * D) return;
    int c = idx % D;
    float v = a[idx] * scsh[c] + scsh[D + c];
    y[idx] = v > 0.f ? v : 0.f;
}

// ---------------------------------------------------------------------------
// log_softmax over OUT_C==64: one wave per node, shuffle reductions.
// ---------------------------------------------------------------------------
__global__ void lsm_kernel(const float* __restrict__ agg,
                           const float* __restrict__ b,
                           float* __restrict__ out, int N) {
    int wave = (blockIdx.x * blockDim.x + threadIdx.x) >> 6;
    int lane = threadIdx.x & 63;
    if (wave >= N) return;
    float v = agg[(long)wave * OUT_C + lane] + b[lane];
    float m = v;
#pragma unroll
    for (int off = 32; off > 0; off >>= 1) m = fmaxf(m, __shfl_xor(m, off, 64));
    float e = expf(v - m);
    float s = e;
#pragma unroll
    for (int off = 32; off > 0; off >>= 1) s += __shfl_xor(s, off, 64);
    out[(long)wave * OUT_C + lane] = v - m - logf(s);
}

extern "C" void kernel_launch(void* const* d_in, const int* in_sizes, int n_in,
                              void* d_out, int out_size, void* d_ws, size_t ws_size,
                              hipStream_t stream) {
    const float* x   = (const float*)d_in[0];
    const float* ew  = (const float*)d_in[1];
    const int*   row = (const int*)d_in[2];
    const int*   col = (const int*)d_in[3];
    const float* W1  = (const float*)d_in[4];
    // b1 = d_in[5], b2 = d_in[7]: cancel inside BatchNorm (see bn_finalize).
    const float* W2  = (const float*)d_in[6];
    const float* W3  = (const float*)d_in[8];
    const float* b3  = (const float*)d_in[9];
    const float* g1  = (const float*)d_in[10];
    const float* be1 = (const float*)d_in[11];
    const float* g2  = (const float*)d_in[12];
    const float* be2 = (const float*)d_in[13];
    float* out = (float*)d_out;

    // Workspace: A[N*96] | B[N*96] | stats[192] | scsh[192] | pairs[E int2] |
    //            rowptr[N+1] | pos[N]
    float* A     = (float*)d_ws;
    float* B     = A + (size_t)N_NODES * HID_C;
    float* stats = B + (size_t)N_NODES * HID_C;
    float* scsh  = stats + 2 * HID_C;
    int2*  pairs = (int2*)(scsh + 2 * HID_C);
    int*   rowptr = (int*)(pairs + N_EDGES);
    int*   pos    = rowptr + (N_NODES + 1);

    const int T = 256;
    const int gridE   = (N_EDGES + T - 1) / T;
    const int gridNH  = (N_NODES * HID_C + T - 1) / T;
    const int gridA96 = (N_NODES * (HID_C / 4) + T - 1) / T;
    const int gridA64 = (N_NODES * (OUT_C / 4) + T - 1) / T;
    const int gridG   = (N_NODES + 63) / 64;   // gemm tiles

    // ---- CSR build (reused by all 3 layers) ----
    hipMemsetAsync(pos, 0, N_NODES * sizeof(int), stream);  // pos doubles as deg
    hist_kernel<<<gridE, T, 0, stream>>>(row, pos);
    scan_kernel<<<1, 1024, 0, stream>>>(pos, rowptr);
    hipMemcpyAsync(pos, rowptr, N_NODES * sizeof(int), hipMemcpyDeviceToDevice, stream);
    fill_kernel<<<gridE, T, 0, stream>>>(row, col, ew, pos, pairs);

    // ---- Layer 1: GCNConv(128->96) + BN + ReLU ----
    gemm_tiled<IN_C, HID_C><<<gridG, (HID_C / 4) * 16, 0, stream>>>(x, W1, A, N_NODES);
    agg_csr_kernel<HID_C><<<gridA96, T, 0, stream>>>(A, rowptr, pairs, B);
    hipMemsetAsync(stats, 0, 2 * HID_C * sizeof(float), stream);
    bn_stats_kernel<HID_C><<<1024, T, 0, stream>>>(B, stats, N_NODES);
    bn_finalize_kernel<HID_C><<<1, 128, 0, stream>>>(stats, g1, be1, scsh, 1.f / N_NODES);
    bn_apply_kernel<HID_C><<<gridNH, T, 0, stream>>>(B, scsh, B, N_NODES);

    // ---- Layer 2: GCNConv(96->96) + BN + ReLU ----
    gemm_tiled<HID_C, HID_C><<<gridG, (HID_C / 4) * 16, 0, stream>>>(B, W2, A, N_NODES);
    agg_csr_kernel<HID_C><<<gridA96, T, 0, stream>>>(A, rowptr, pairs, B);
    hipMemsetAsync(stats, 0, 2 * HID_C * sizeof(float), stream);
    bn_stats_kernel<HID_C><<<1024, T, 0, stream>>>(B, stats, N_NODES);
    bn_finalize_kernel<HID_C><<<1, 128, 0, stream>>>(stats, g2, be2, scsh, 1.f / N_NODES);
    bn_apply_kernel<HID_C><<<gridNH, T, 0, stream>>>(B, scsh, B, N_NODES);

    // ---- Layer 3: GCNConv(96->64) + log_softmax (agg direct into d_out) ----
    gemm_tiled<HID_C, OUT_C><<<gridG, (OUT_C / 4) * 16, 0, stream>>>(B, W3, A, N_NODES);
    agg_csr_kernel<OUT_C><<<gridA64, T, 0, stream>>>(A, rowptr, pairs, out);
    lsm_kernel<<<(N_NODES + 3) / 4, T, 0, stream>>>(out, b3, out, N_NODES);
}

// Round 4
// 532.168 us; speedup vs baseline: 6.3482x; 1.1467x over previous
//
#include <hip/hip_runtime.h>
#include <math.h>

#define N_NODES 50000
#define N_EDGES 800000
#define IN_C 128
#define HID_C 96
#define OUT_C 64
#define BN_EPS 1e-5f

// ---------------------------------------------------------------------------
// Register-tiled GEMM: h[N,J] = x[N,K] @ W[K,J], optionally fusing the
// PREVIOUS layer's BN scale/shift + ReLU into the x staging load (APPLY).
// Tile: 64 nodes x J channels. W fully in LDS; x staged transposed in
// K-chunks of 32. Thread computes a 4x4 register tile.
// ---------------------------------------------------------------------------
template <int K, int J, bool APPLY>
__global__ void gemm_tiled(const float* __restrict__ x,
                           const float* __restrict__ W,
                           const float* __restrict__ scsh,  // [sc[K], sh[K]]
                           float* __restrict__ h, int N) {
    constexpr int MT = 64, TM = 4, TN = 4, KB = 32;
    constexpr int TX = J / TN;       // 24 (J=96) or 16 (J=64)
    constexpr int XP = MT + 4;       // padded XsT row
    __shared__ __align__(16) float Ws[K * J];
    __shared__ __align__(16) float XsT[KB * XP];

    int tid = threadIdx.x;
    int tx = tid % TX, ty = tid / TX;
    int tileBase = blockIdx.x * MT;

    for (int i = tid; i < K * J / 4; i += blockDim.x)
        ((float4*)Ws)[i] = ((const float4*)W)[i];

    float4 acc[TM];
#pragma unroll
    for (int tm = 0; tm < TM; ++tm) acc[tm] = make_float4(0.f, 0.f, 0.f, 0.f);

    for (int k0 = 0; k0 < K; k0 += KB) {
        __syncthreads();
        for (int i = tid; i < MT * (KB / 4); i += blockDim.x) {
            int node = i / (KB / 4), kq = i % (KB / 4);
            int gn = min(tileBase + node, N - 1);
            float4 v = *(const float4*)(x + (size_t)gn * K + k0 + kq * 4);
            if (APPLY) {
                int kb = k0 + kq * 4;
                v.x = fmaxf(v.x * scsh[kb + 0] + scsh[K + kb + 0], 0.f);
                v.y = fmaxf(v.y * scsh[kb + 1] + scsh[K + kb + 1], 0.f);
                v.z = fmaxf(v.z * scsh[kb + 2] + scsh[K + kb + 2], 0.f);
                v.w = fmaxf(v.w * scsh[kb + 3] + scsh[K + kb + 3], 0.f);
            }
            XsT[(kq * 4 + 0) * XP + node] = v.x;
            XsT[(kq * 4 + 1) * XP + node] = v.y;
            XsT[(kq * 4 + 2) * XP + node] = v.z;
            XsT[(kq * 4 + 3) * XP + node] = v.w;
        }
        __syncthreads();
#pragma unroll 8
        for (int kk = 0; kk < KB; ++kk) {
            float4 a = *(const float4*)&XsT[kk * XP + ty * TM];
            float4 b = *(const float4*)&Ws[(k0 + kk) * J + tx * TN];
#pragma unroll
            for (int tm = 0; tm < TM; ++tm) {
                float av = ((const float*)&a)[tm];
                acc[tm].x += av * b.x;
                acc[tm].y += av * b.y;
                acc[tm].z += av * b.z;
                acc[tm].w += av * b.w;
            }
        }
    }
#pragma unroll
    for (int tm = 0; tm < TM; ++tm) {
        int n = tileBase + ty * TM + tm;
        if (n < N) *(float4*)(h + (size_t)n * J + tx * TN) = acc[tm];
    }
}

// ---------------------------------------------------------------------------
// CSR build: histogram -> hierarchical scan (3 parallel stages) -> fill.
// ---------------------------------------------------------------------------
__global__ void hist_kernel(const int* __restrict__ row, int* __restrict__ deg) {
    int e = blockIdx.x * blockDim.x + threadIdx.x;
    if (e < N_EDGES) atomicAdd(&deg[row[e]], 1);
}

#define SCAN_B 256
#define SCAN_NB ((N_NODES + SCAN_B - 1) / SCAN_B)   // 196

// Stage A: per-block sums of deg.
__global__ void scanA_kernel(const int* __restrict__ deg, int* __restrict__ part) {
    __shared__ int s[SCAN_B];
    int i = blockIdx.x * SCAN_B + threadIdx.x;
    s[threadIdx.x] = (i < N_NODES) ? deg[i] : 0;
    __syncthreads();
    for (int off = SCAN_B / 2; off > 0; off >>= 1) {
        if (threadIdx.x < off) s[threadIdx.x] += s[threadIdx.x + off];
        __syncthreads();
    }
    if (threadIdx.x == 0) part[blockIdx.x] = s[0];
}

// Stage B: one block scans the partials; part[t] <- exclusive block offset.
__global__ void scanB_kernel(int* __restrict__ part, int* __restrict__ rowptr) {
    __shared__ int s[SCAN_B];
    int t = threadIdx.x;
    s[t] = (t < SCAN_NB) ? part[t] : 0;
    __syncthreads();
    for (int off = 1; off < SCAN_B; off <<= 1) {
        int v = 0;
        if (t >= off) v = s[t - off];
        __syncthreads();
        if (t >= off) s[t] += v;
        __syncthreads();
    }
    if (t < SCAN_NB) part[t] = (t == 0) ? 0 : s[t - 1];   // exclusive
    if (t == 0) rowptr[N_NODES] = s[SCAN_NB - 1];         // total = N_EDGES
}

// Stage C: per-block exclusive scan of deg + block offset; writes rowptr & pos.
__global__ void scanC_kernel(const int* __restrict__ deg,
                             const int* __restrict__ part,
                             int* __restrict__ rowptr, int* __restrict__ pos) {
    __shared__ int s[SCAN_B];
    int t = threadIdx.x;
    int i = blockIdx.x * SCAN_B + t;
    int d = (i < N_NODES) ? deg[i] : 0;
    s[t] = d;
    __syncthreads();
    for (int off = 1; off < SCAN_B; off <<= 1) {
        int v = 0;
        if (t >= off) v = s[t - off];
        __syncthreads();
        if (t >= off) s[t] += v;
        __syncthreads();
    }
    if (i < N_NODES) {
        int r = part[blockIdx.x] + s[t] - d;   // exclusive
        rowptr[i] = r;
        pos[i] = r;
    }
}

__global__ void fill_kernel(const int* __restrict__ row, const int* __restrict__ col,
                            const float* __restrict__ ew, int* __restrict__ pos,
                            int2* __restrict__ pairs) {
    int e = blockIdx.x * blockDim.x + threadIdx.x;
    if (e >= N_EDGES) return;
    int idx = atomicAdd(&pos[row[e]], 1);
    pairs[idx] = make_int2(col[e], __float_as_int(ew[e]));
}

// ---------------------------------------------------------------------------
// CSR aggregation: thread per (node, float4 group); register accumulate.
// ---------------------------------------------------------------------------
template <int D>
__global__ void agg_csr_kernel(const float* __restrict__ h,
                               const int* __restrict__ rowptr,
                               const int2* __restrict__ pairs,
                               float* __restrict__ out) {
    const int G = D / 4;
    int t = blockIdx.x * blockDim.x + threadIdx.x;
    if (t >= N_NODES * G) return;
    int n = t / G, g = t % G;
    int beg = rowptr[n], end = rowptr[n + 1];
    float4 acc = make_float4(0.f, 0.f, 0.f, 0.f);
    for (int i = beg; i < end; ++i) {
        int2 p = pairs[i];
        float w = __int_as_float(p.y);
        const float4 v = *(const float4*)(h + (size_t)p.x * D + g * 4);
        acc.x += w * v.x; acc.y += w * v.y; acc.z += w * v.z; acc.w += w * v.w;
    }
    *(float4*)(out + (size_t)n * D + g * 4) = acc;
}

// ---------------------------------------------------------------------------
// BN stats + finalize. Conv bias cancels inside BN. Apply is fused into the
// next gemm's staging load.
// ---------------------------------------------------------------------------
template <int D>
__global__ void bn_stats_kernel(const float* __restrict__ a,
                                float* __restrict__ sums, int N) {
    __shared__ float s[D], ss[D];
    for (int i = threadIdx.x; i < D; i += blockDim.x) { s[i] = 0.f; ss[i] = 0.f; }
    __syncthreads();
    int total = N * D;
    for (int idx = blockIdx.x * blockDim.x + threadIdx.x; idx < total;
         idx += gridDim.x * blockDim.x) {
        float v = a[idx];
        int ch = idx % D;
        atomicAdd(&s[ch], v);
        atomicAdd(&ss[ch], v * v);
    }
    __syncthreads();
    for (int i = threadIdx.x; i < D; i += blockDim.x) {
        atomicAdd(&sums[i], s[i]);
        atomicAdd(&sums[D + i], ss[i]);
    }
}

template <int D>
__global__ void bn_finalize_kernel(const float* __restrict__ sums,
                                   const float* __restrict__ g,
                                   const float* __restrict__ be,
                                   float* __restrict__ scsh, float invN) {
    int c = threadIdx.x;
    if (c < D) {
        float mean = sums[c] * invN;
        float var = sums[D + c] * invN - mean * mean;
        float sc = g[c] * rsqrtf(var + BN_EPS);
        scsh[c] = sc;
        scsh[D + c] = be[c] - mean * sc;
    }
}

// ---------------------------------------------------------------------------
// log_softmax over OUT_C==64: one wave per node, shuffle reductions.
// ---------------------------------------------------------------------------
__global__ void lsm_kernel(const float* __restrict__ agg,
                           const float* __restrict__ b,
                           float* __restrict__ out, int N) {
    int wave = (blockIdx.x * blockDim.x + threadIdx.x) >> 6;
    int lane = threadIdx.x & 63;
    if (wave >= N) return;
    float v = agg[(long)wave * OUT_C + lane] + b[lane];
    float m = v;
#pragma unroll
    for (int off = 32; off > 0; off >>= 1) m = fmaxf(m, __shfl_xor(m, off, 64));
    float e = expf(v - m);
    float s = e;
#pragma unroll
    for (int off = 32; off > 0; off >>= 1) s += __shfl_xor(s, off, 64);
    out[(long)wave * OUT_C + lane] = v - m - logf(s);
}

extern "C" void kernel_launch(void* const* d_in, const int* in_sizes, int n_in,
                              void* d_out, int out_size, void* d_ws, size_t ws_size,
                              hipStream_t stream) {
    const float* x   = (const float*)d_in[0];
    const float* ew  = (const float*)d_in[1];
    const int*   row = (const int*)d_in[2];
    const int*   col = (const int*)d_in[3];
    const float* W1  = (const float*)d_in[4];
    // b1 = d_in[5], b2 = d_in[7]: cancel inside BatchNorm (see bn_finalize).
    const float* W2  = (const float*)d_in[6];
    const float* W3  = (const float*)d_in[8];
    const float* b3  = (const float*)d_in[9];
    const float* g1  = (const float*)d_in[10];
    const float* be1 = (const float*)d_in[11];
    const float* g2  = (const float*)d_in[12];
    const float* be2 = (const float*)d_in[13];
    float* out = (float*)d_out;

    // Workspace: A[N*96] | B[N*96] | stats[192] | scsh1[192] | scsh2[192] |
    //            pairs[E int2] | rowptr[N+1] | deg[N] | pos[N] | part[SCAN_NB]
    float* A     = (float*)d_ws;
    float* B     = A + (size_t)N_NODES * HID_C;
    float* stats = B + (size_t)N_NODES * HID_C;
    float* scsh1 = stats + 2 * HID_C;
    float* scsh2 = scsh1 + 2 * HID_C;
    int2*  pairs = (int2*)(scsh2 + 2 * HID_C);
    int*   rowptr = (int*)(pairs + N_EDGES);
    int*   deg    = rowptr + (N_NODES + 1);
    int*   pos    = deg + N_NODES;
    int*   part   = pos + N_NODES;

    const int T = 256;
    const int gridE   = (N_EDGES + T - 1) / T;
    const int gridA96 = (N_NODES * (HID_C / 4) + T - 1) / T;
    const int gridA64 = (N_NODES * (OUT_C / 4) + T - 1) / T;
    const int gridG   = (N_NODES + 63) / 64;

    // ---- CSR build (hierarchical scan; reused by all 3 layers) ----
    hipMemsetAsync(deg, 0, N_NODES * sizeof(int), stream);
    hist_kernel<<<gridE, T, 0, stream>>>(row, deg);
    scanA_kernel<<<SCAN_NB, SCAN_B, 0, stream>>>(deg, part);
    scanB_kernel<<<1, SCAN_B, 0, stream>>>(part, rowptr);
    scanC_kernel<<<SCAN_NB, SCAN_B, 0, stream>>>(deg, part, rowptr, pos);
    fill_kernel<<<gridE, T, 0, stream>>>(row, col, ew, pos, pairs);

    // ---- Layer 1: GCNConv(128->96) + BN stats ----
    gemm_tiled<IN_C, HID_C, false><<<gridG, (HID_C / 4) * 16, 0, stream>>>(
        x, W1, nullptr, A, N_NODES);
    agg_csr_kernel<HID_C><<<gridA96, T, 0, stream>>>(A, rowptr, pairs, B);
    hipMemsetAsync(stats, 0, 2 * HID_C * sizeof(float), stream);
    bn_stats_kernel<HID_C><<<1024, T, 0, stream>>>(B, stats, N_NODES);
    bn_finalize_kernel<HID_C><<<1, 128, 0, stream>>>(stats, g1, be1, scsh1, 1.f / N_NODES);

    // ---- Layer 2: (BN1+ReLU fused into gemm) GCNConv(96->96) + BN stats ----
    gemm_tiled<HID_C, HID_C, true><<<gridG, (HID_C / 4) * 16, 0, stream>>>(
        B, W2, scsh1, A, N_NODES);
    agg_csr_kernel<HID_C><<<gridA96, T, 0, stream>>>(A, rowptr, pairs, B);
    hipMemsetAsync(stats, 0, 2 * HID_C * sizeof(float), stream);
    bn_stats_kernel<HID_C><<<1024, T, 0, stream>>>(B, stats, N_NODES);
    bn_finalize_kernel<HID_C><<<1, 128, 0, stream>>>(stats, g2, be2, scsh2, 1.f / N_NODES);

    // ---- Layer 3: (BN2+ReLU fused) GCNConv(96->64) + agg into out + lsm ----
    gemm_tiled<HID_C, OUT_C, true><<<gridG, (OUT_C / 4) * 16, 0, stream>>>(
        B, W3, scsh2, A, N_NODES);
    agg_csr_kernel<OUT_C><<<gridA64, T, 0, stream>>>(A, rowptr, pairs, out);
    lsm_kernel<<<(N_NODES + 3) / 4, T, 0, stream>>>(out, b3, out, N_NODES);
}

// Round 5
// 444.865 us; speedup vs baseline: 7.5939x; 1.1962x over previous
//
#include <hip/hip_runtime.h>
#include <math.h>

#define N_NODES 50000
#define N_EDGES 800000
#define IN_C 128
#define HID_C 96
#define OUT_C 64
#define BN_EPS 1e-5f

// ---------------------------------------------------------------------------
// Register-tiled GEMM: h[N,J] = x[N,K] @ W[K,J], optionally fusing the
// PREVIOUS layer's BN scale/shift + ReLU into the x staging load (APPLY).
// Tile: 64 nodes x J channels. W fully in LDS; x staged transposed in
// K-chunks of 32. Thread computes a 4x4 register tile.
// ---------------------------------------------------------------------------
template <int K, int J, bool APPLY>
__global__ void gemm_tiled(const float* __restrict__ x,
                           const float* __restrict__ W,
                           const float* __restrict__ scsh,  // [sc[K], sh[K]]
                           float* __restrict__ h, int N) {
    constexpr int MT = 64, TM = 4, TN = 4, KB = 32;
    constexpr int TX = J / TN;       // 24 (J=96) or 16 (J=64)
    constexpr int XP = MT + 4;       // padded XsT row
    __shared__ __align__(16) float Ws[K * J];
    __shared__ __align__(16) float XsT[KB * XP];

    int tid = threadIdx.x;
    int tx = tid % TX, ty = tid / TX;
    int tileBase = blockIdx.x * MT;

    for (int i = tid; i < K * J / 4; i += blockDim.x)
        ((float4*)Ws)[i] = ((const float4*)W)[i];

    float4 acc[TM];
#pragma unroll
    for (int tm = 0; tm < TM; ++tm) acc[tm] = make_float4(0.f, 0.f, 0.f, 0.f);

    for (int k0 = 0; k0 < K; k0 += KB) {
        __syncthreads();
        for (int i = tid; i < MT * (KB / 4); i += blockDim.x) {
            int node = i / (KB / 4), kq = i % (KB / 4);
            int gn = min(tileBase + node, N - 1);
            float4 v = *(const float4*)(x + (size_t)gn * K + k0 + kq * 4);
            if (APPLY) {
                int kb = k0 + kq * 4;
                v.x = fmaxf(v.x * scsh[kb + 0] + scsh[K + kb + 0], 0.f);
                v.y = fmaxf(v.y * scsh[kb + 1] + scsh[K + kb + 1], 0.f);
                v.z = fmaxf(v.z * scsh[kb + 2] + scsh[K + kb + 2], 0.f);
                v.w = fmaxf(v.w * scsh[kb + 3] + scsh[K + kb + 3], 0.f);
            }
            XsT[(kq * 4 + 0) * XP + node] = v.x;
            XsT[(kq * 4 + 1) * XP + node] = v.y;
            XsT[(kq * 4 + 2) * XP + node] = v.z;
            XsT[(kq * 4 + 3) * XP + node] = v.w;
        }
        __syncthreads();
#pragma unroll 8
        for (int kk = 0; kk < KB; ++kk) {
            float4 a = *(const float4*)&XsT[kk * XP + ty * TM];
            float4 b = *(const float4*)&Ws[(k0 + kk) * J + tx * TN];
#pragma unroll
            for (int tm = 0; tm < TM; ++tm) {
                float av = ((const float*)&a)[tm];
                acc[tm].x += av * b.x;
                acc[tm].y += av * b.y;
                acc[tm].z += av * b.z;
                acc[tm].w += av * b.w;
            }
        }
    }
#pragma unroll
    for (int tm = 0; tm < TM; ++tm) {
        int n = tileBase + ty * TM + tm;
        if (n < N) *(float4*)(h + (size_t)n * J + tx * TN) = acc[tm];
    }
}

// ---------------------------------------------------------------------------
// CSR build: histogram -> hierarchical scan (3 parallel stages) -> fill.
// ---------------------------------------------------------------------------
__global__ void hist_kernel(const int* __restrict__ row, int* __restrict__ deg) {
    int e = blockIdx.x * blockDim.x + threadIdx.x;
    if (e < N_EDGES) atomicAdd(&deg[row[e]], 1);
}

#define SCAN_B 256
#define SCAN_NB ((N_NODES + SCAN_B - 1) / SCAN_B)   // 196

__global__ void scanA_kernel(const int* __restrict__ deg, int* __restrict__ part) {
    __shared__ int s[SCAN_B];
    int i = blockIdx.x * SCAN_B + threadIdx.x;
    s[threadIdx.x] = (i < N_NODES) ? deg[i] : 0;
    __syncthreads();
    for (int off = SCAN_B / 2; off > 0; off >>= 1) {
        if (threadIdx.x < off) s[threadIdx.x] += s[threadIdx.x + off];
        __syncthreads();
    }
    if (threadIdx.x == 0) part[blockIdx.x] = s[0];
}

__global__ void scanB_kernel(int* __restrict__ part, int* __restrict__ rowptr) {
    __shared__ int s[SCAN_B];
    int t = threadIdx.x;
    s[t] = (t < SCAN_NB) ? part[t] : 0;
    __syncthreads();
    for (int off = 1; off < SCAN_B; off <<= 1) {
        int v = 0;
        if (t >= off) v = s[t - off];
        __syncthreads();
        if (t >= off) s[t] += v;
        __syncthreads();
    }
    if (t < SCAN_NB) part[t] = (t == 0) ? 0 : s[t - 1];   // exclusive
    if (t == 0) rowptr[N_NODES] = s[SCAN_NB - 1];         // total = N_EDGES
}

__global__ void scanC_kernel(const int* __restrict__ deg,
                             const int* __restrict__ part,
                             int* __restrict__ rowptr, int* __restrict__ pos) {
    __shared__ int s[SCAN_B];
    int t = threadIdx.x;
    int i = blockIdx.x * SCAN_B + t;
    int d = (i < N_NODES) ? deg[i] : 0;
    s[t] = d;
    __syncthreads();
    for (int off = 1; off < SCAN_B; off <<= 1) {
        int v = 0;
        if (t >= off) v = s[t - off];
        __syncthreads();
        if (t >= off) s[t] += v;
        __syncthreads();
    }
    if (i < N_NODES) {
        int r = part[blockIdx.x] + s[t] - d;   // exclusive
        rowptr[i] = r;
        pos[i] = r;
    }
}

__global__ void fill_kernel(const int* __restrict__ row, const int* __restrict__ col,
                            const float* __restrict__ ew, int* __restrict__ pos,
                            int2* __restrict__ pairs) {
    int e = blockIdx.x * blockDim.x + threadIdx.x;
    if (e >= N_EDGES) return;
    int idx = atomicAdd(&pos[row[e]], 1);
    pairs[idx] = make_int2(col[e], __float_as_int(ew[e]));
}

// ---------------------------------------------------------------------------
// CSR aggregation: thread per (node, float4 group); register accumulate.
// ---------------------------------------------------------------------------
template <int D>
__global__ void agg_csr_kernel(const float* __restrict__ h,
                               const int* __restrict__ rowptr,
                               const int2* __restrict__ pairs,
                               float* __restrict__ out) {
    const int G = D / 4;
    int t = blockIdx.x * blockDim.x + threadIdx.x;
    if (t >= N_NODES * G) return;
    int n = t / G, g = t % G;
    int beg = rowptr[n], end = rowptr[n + 1];
    float4 acc = make_float4(0.f, 0.f, 0.f, 0.f);
    for (int i = beg; i < end; ++i) {
        int2 p = pairs[i];
        float w = __int_as_float(p.y);
        const float4 v = *(const float4*)(h + (size_t)p.x * D + g * 4);
        acc.x += w * v.x; acc.y += w * v.y; acc.z += w * v.z; acc.w += w * v.w;
    }
    *(float4*)(out + (size_t)n * D + g * 4) = acc;
}

// ---------------------------------------------------------------------------
// BN stats, register-accumulation version. Block = 384 threads = 16 rows x
// 24 float4-groups: thread owns 4 fixed channels, accumulates sum/sumsq in
// registers over a grid-stride row loop (coalesced float4 loads, no LDS in
// the hot loop). Epilogue: LDS transpose-reduce of the 16 row-copies, then
// 192 global atomics per block.
// ---------------------------------------------------------------------------
#define STATS_BLOCKS 250

template <int D>
__global__ void bn_stats_kernel(const float* __restrict__ a,
                                float* __restrict__ sums, int N) {
    constexpr int G = D / 4;       // 24
    constexpr int ROWS = 384 / G;  // 16
    int t = threadIdx.x;
    int g = t % G, r0 = t / G;
    float4 s4 = make_float4(0.f, 0.f, 0.f, 0.f);
    float4 q4 = make_float4(0.f, 0.f, 0.f, 0.f);
    for (int r = blockIdx.x * ROWS + r0; r < N; r += gridDim.x * ROWS) {
        float4 v = *(const float4*)(a + (size_t)r * D + g * 4);
        s4.x += v.x; s4.y += v.y; s4.z += v.z; s4.w += v.w;
        q4.x += v.x * v.x; q4.y += v.y * v.y; q4.z += v.z * v.z; q4.w += v.w * v.w;
    }
    __shared__ __align__(16) float sh[2 * ROWS * D];
    *(float4*)&sh[r0 * D + g * 4] = s4;
    *(float4*)&sh[ROWS * D + r0 * D + g * 4] = q4;
    __syncthreads();
    if (t < D) {
        float s0 = 0.f, s1 = 0.f;
#pragma unroll
        for (int k = 0; k < ROWS; ++k) {
            s0 += sh[k * D + t];
            s1 += sh[ROWS * D + k * D + t];
        }
        atomicAdd(&sums[t], s0);
        atomicAdd(&sums[D + t], s1);
    }
}

template <int D>
__global__ void bn_finalize_kernel(const float* __restrict__ sums,
                                   const float* __restrict__ g,
                                   const float* __restrict__ be,
                                   float* __restrict__ scsh, float invN) {
    int c = threadIdx.x;
    if (c < D) {
        float mean = sums[c] * invN;
        float var = sums[D + c] * invN - mean * mean;
        float sc = g[c] * rsqrtf(var + BN_EPS);
        scsh[c] = sc;
        scsh[D + c] = be[c] - mean * sc;
    }
}

// ---------------------------------------------------------------------------
// log_softmax over OUT_C==64: one wave per node, shuffle reductions.
// ---------------------------------------------------------------------------
__global__ void lsm_kernel(const float* __restrict__ agg,
                           const float* __restrict__ b,
                           float* __restrict__ out, int N) {
    int wave = (blockIdx.x * blockDim.x + threadIdx.x) >> 6;
    int lane = threadIdx.x & 63;
    if (wave >= N) return;
    float v = agg[(long)wave * OUT_C + lane] + b[lane];
    float m = v;
#pragma unroll
    for (int off = 32; off > 0; off >>= 1) m = fmaxf(m, __shfl_xor(m, off, 64));
    float e = expf(v - m);
    float s = e;
#pragma unroll
    for (int off = 32; off > 0; off >>= 1) s += __shfl_xor(s, off, 64);
    out[(long)wave * OUT_C + lane] = v - m - logf(s);
}

extern "C" void kernel_launch(void* const* d_in, const int* in_sizes, int n_in,
                              void* d_out, int out_size, void* d_ws, size_t ws_size,
                              hipStream_t stream) {
    const float* x   = (const float*)d_in[0];
    const float* ew  = (const float*)d_in[1];
    const int*   row = (const int*)d_in[2];
    const int*   col = (const int*)d_in[3];
    const float* W1  = (const float*)d_in[4];
    // b1 = d_in[5], b2 = d_in[7]: cancel inside BatchNorm (see bn_finalize).
    const float* W2  = (const float*)d_in[6];
    const float* W3  = (const float*)d_in[8];
    const float* b3  = (const float*)d_in[9];
    const float* g1  = (const float*)d_in[10];
    const float* be1 = (const float*)d_in[11];
    const float* g2  = (const float*)d_in[12];
    const float* be2 = (const float*)d_in[13];
    float* out = (float*)d_out;

    // Workspace: A[N*96] | B[N*96] | stats[192] | scsh1[192] | scsh2[192] |
    //            pairs[E int2] | rowptr[N+1] | deg[N] | pos[N] | part[SCAN_NB]
    float* A     = (float*)d_ws;
    float* B     = A + (size_t)N_NODES * HID_C;
    float* stats = B + (size_t)N_NODES * HID_C;
    float* scsh1 = stats + 2 * HID_C;
    float* scsh2 = scsh1 + 2 * HID_C;
    int2*  pairs = (int2*)(scsh2 + 2 * HID_C);
    int*   rowptr = (int*)(pairs + N_EDGES);
    int*   deg    = rowptr + (N_NODES + 1);
    int*   pos    = deg + N_NODES;
    int*   part   = pos + N_NODES;

    const int T = 256;
    const int gridE   = (N_EDGES + T - 1) / T;
    const int gridA96 = (N_NODES * (HID_C / 4) + T - 1) / T;
    const int gridA64 = (N_NODES * (OUT_C / 4) + T - 1) / T;
    const int gridG   = (N_NODES + 63) / 64;

    // ---- CSR build (hierarchical scan; reused by all 3 layers) ----
    hipMemsetAsync(deg, 0, N_NODES * sizeof(int), stream);
    hist_kernel<<<gridE, T, 0, stream>>>(row, deg);
    scanA_kernel<<<SCAN_NB, SCAN_B, 0, stream>>>(deg, part);
    scanB_kernel<<<1, SCAN_B, 0, stream>>>(part, rowptr);
    scanC_kernel<<<SCAN_NB, SCAN_B, 0, stream>>>(deg, part, rowptr, pos);
    fill_kernel<<<gridE, T, 0, stream>>>(row, col, ew, pos, pairs);

    // ---- Layer 1: GCNConv(128->96) + BN stats ----
    gemm_tiled<IN_C, HID_C, false><<<gridG, (HID_C / 4) * 16, 0, stream>>>(
        x, W1, nullptr, A, N_NODES);
    agg_csr_kernel<HID_C><<<gridA96, T, 0, stream>>>(A, rowptr, pairs, B);
    hipMemsetAsync(stats, 0, 2 * HID_C * sizeof(float), stream);
    bn_stats_kernel<HID_C><<<STATS_BLOCKS, 384, 0, stream>>>(B, stats, N_NODES);
    bn_finalize_kernel<HID_C><<<1, 128, 0, stream>>>(stats, g1, be1, scsh1, 1.f / N_NODES);

    // ---- Layer 2: (BN1+ReLU fused into gemm) GCNConv(96->96) + BN stats ----
    gemm_tiled<HID_C, HID_C, true><<<gridG, (HID_C / 4) * 16, 0, stream>>>(
        B, W2, scsh1, A, N_NODES);
    agg_csr_kernel<HID_C><<<gridA96, T, 0, stream>>>(A, rowptr, pairs, B);
    hipMemsetAsync(stats, 0, 2 * HID_C * sizeof(float), stream);
    bn_stats_kernel<HID_C><<<STATS_BLOCKS, 384, 0, stream>>>(B, stats, N_NODES);
    bn_finalize_kernel<HID_C><<<1, 128, 0, stream>>>(stats, g2, be2, scsh2, 1.f / N_NODES);

    // ---- Layer 3: (BN2+ReLU fused) GCNConv(96->64) + agg into out + lsm ----
    gemm_tiled<HID_C, OUT_C, true><<<gridG, (OUT_C / 4) * 16, 0, stream>>>(
        B, W3, scsh2, A, N_NODES);
    agg_csr_kernel<OUT_C><<<gridA64, T, 0, stream>>>(A, rowptr, pairs, out);
    lsm_kernel<<<(N_NODES + 3) / 4, T, 0, stream>>>(out, b3, out, N_NODES);
}